// Round 1
// baseline (690.126 us; speedup 1.0000x reference)
//
#include <hip/hip_runtime.h>
#include <hip/hip_bf16.h>

#define NN 50000
#define NE 800000
#define DIM 128

typedef __attribute__((ext_vector_type(8))) short bf16x8;
typedef __attribute__((ext_vector_type(4))) float f32x4;

__device__ __forceinline__ short f2bf(float f) {
    union { float f; unsigned u; } x; x.f = f;
    unsigned r = x.u + 0x7fffu + ((x.u >> 16) & 1u);   // RNE
    return (short)(r >> 16);
}

__device__ __forceinline__ bf16x8 pack8(float4 a, float4 b) {
    bf16x8 v;
    v[0] = f2bf(a.x); v[1] = f2bf(a.y); v[2] = f2bf(a.z); v[3] = f2bf(a.w);
    v[4] = f2bf(b.x); v[5] = f2bf(b.y); v[6] = f2bf(b.z); v[7] = f2bf(b.w);
    return v;
}

// ---------------------------------------------------------------------------
// Kernel 1: agg[dst] += X[src]  (raw-feature aggregation; linearity of W)
// One wave per edge per iteration; lane handles 2 consecutive floats.
// ---------------------------------------------------------------------------
__global__ __launch_bounds__(256) void scatter_k(
        const float* __restrict__ X,
        const int*   __restrict__ src,
        const int*   __restrict__ dst,
        float*       __restrict__ agg) {
    int lane = threadIdx.x & 63;
    int gw   = (blockIdx.x * 256 + threadIdx.x) >> 6;
    int nw   = (gridDim.x * 256) >> 6;
    for (int e = gw; e < NE; e += nw) {
        int s = src[e];
        int d = dst[e];
        float2 v = *(const float2*)(X + (size_t)s * DIM + lane * 2);
        float* a = agg + (size_t)d * DIM + lane * 2;
        unsafeAtomicAdd(a,     v.x);   // global_atomic_add_f32
        unsafeAtomicAdd(a + 1, v.y);
    }
}

// ---------------------------------------------------------------------------
// Kernel 2: out = ReLU(X @ Ws^T + agg @ Wn^T + bias)   (agg aliases out!)
// bf16 MFMA 16x16x32, fp32 accumulate. Block = 256 thr = 4 waves.
// Block tile: 64 nodes x 128 outputs; wave w owns rows [n0+16w, n0+16w+16).
// Safe in-place: each wave reads agg only from the rows it later writes.
// ---------------------------------------------------------------------------
__global__ __launch_bounds__(256) void fused_gemm(
        const float* __restrict__ X,
        const float* __restrict__ agg,
        const float* __restrict__ Ws,
        const float* __restrict__ Wn,
        const float* __restrict__ bias,
        float*       __restrict__ out) {
    // Both W matrices in LDS as bf16, XOR-swizzled (16B granularity) so that
    // B-fragment ds_read_b128 (16 rows @ 256B stride) is bank-conflict-free.
    __shared__ __align__(16) short wlds[2][128][128];

    // Stage + convert + swizzle W. 128 rows x 16 chunks of 8 cols.
    for (int i = threadIdx.x; i < 128 * 16; i += 256) {
        int row = i >> 4;
        int c8  = (i & 15) << 3;
        int sc  = c8 ^ ((row & 15) << 3);   // swizzle in short units (==<<4 bytes)
        const float4* ps = (const float4*)(Ws + row * DIM + c8);
        *(bf16x8*)&wlds[0][row][sc] = pack8(ps[0], ps[1]);
        const float4* pn = (const float4*)(Wn + row * DIM + c8);
        *(bf16x8*)&wlds[1][row][sc] = pack8(pn[0], pn[1]);
    }
    __syncthreads();

    int lane = threadIdx.x & 63;
    int wv   = threadIdx.x >> 6;                 // 0..3
    int n0   = blockIdx.x * 64 + wv * 16;        // this wave's first row
    int arow = n0 + (lane & 15);
    int rowc = arow < NN ? arow : (NN - 1);      // clamp tail reads (stores guarded)
    const float* xr = X   + (size_t)rowc * DIM + (lane >> 4) * 8;
    const float* ar = agg + (size_t)rowc * DIM + (lane >> 4) * 8;

    f32x4 acc[8] = {};                            // 8 o-tiles of 16

    #pragma unroll
    for (int ks = 0; ks < 4; ++ks) {             // K = 128 in steps of 32
        int k0 = ks * 32;
        float4 xa = *(const float4*)(xr + k0);
        float4 xb = *(const float4*)(xr + k0 + 4);
        bf16x8 afx = pack8(xa, xb);
        float4 ga = *(const float4*)(ar + k0);
        float4 gb = *(const float4*)(ar + k0 + 4);
        bf16x8 afg = pack8(ga, gb);

        int bcol = k0 + (lane >> 4) * 8;
        #pragma unroll
        for (int ot = 0; ot < 8; ++ot) {
            int brow = ot * 16 + (lane & 15);
            int sc   = bcol ^ ((brow & 15) << 3);
            bf16x8 bs = *(const bf16x8*)&wlds[0][brow][sc];
            bf16x8 bn = *(const bf16x8*)&wlds[1][brow][sc];
            acc[ot] = __builtin_amdgcn_mfma_f32_16x16x32_bf16(afx, bs, acc[ot], 0, 0, 0);
            acc[ot] = __builtin_amdgcn_mfma_f32_16x16x32_bf16(afg, bn, acc[ot], 0, 0, 0);
        }
    }

    // Epilogue: D layout col = lane&15, row = (lane>>4)*4 + i  [verified m89]
    int col0  = lane & 15;
    int rbase = n0 + (lane >> 4) * 4;
    #pragma unroll
    for (int ot = 0; ot < 8; ++ot) {
        int col = ot * 16 + col0;
        float bv = bias[col];
        #pragma unroll
        for (int i = 0; i < 4; ++i) {
            int r = rbase + i;
            if (r < NN) out[(size_t)r * DIM + col] = fmaxf(acc[ot][i] + bv, 0.f);
        }
    }
}

// ---------------------------------------------------------------------------
extern "C" void kernel_launch(void* const* d_in, const int* in_sizes, int n_in,
                              void* d_out, int out_size, void* d_ws, size_t ws_size,
                              hipStream_t stream) {
    const float* X    = (const float*)d_in[0];
    const int*   src  = (const int*)  d_in[1];
    const int*   dst  = (const int*)  d_in[2];
    const float* Ws   = (const float*)d_in[3];
    const float* Wn   = (const float*)d_in[4];
    const float* bias = (const float*)d_in[5];
    float* out = (float*)d_out;

    // agg lives in d_out (same shape); zero it, scatter raw X, then fused GEMM
    // reads agg per-row and overwrites the same rows in place.
    hipMemsetAsync(out, 0, (size_t)NN * DIM * sizeof(float), stream);
    scatter_k<<<2048, 256, 0, stream>>>(X, src, dst, out);
    fused_gemm<<<(NN + 63) / 64, 256, 0, stream>>>(X, out, Ws, Wn, bias, out);
}

// Round 2
// 188.805 us; speedup vs baseline: 3.6552x; 3.6552x over previous
//
#include <hip/hip_runtime.h>
#include <hip/hip_bf16.h>

#define NN 50000
#define NE 800000
#define DIM 128
#define NBLK 49   // ceil(NN/1024)

typedef __attribute__((ext_vector_type(8))) short bf16x8;
typedef __attribute__((ext_vector_type(4))) float f32x4;

__device__ __forceinline__ short f2bf(float f) {
    union { float f; unsigned u; } x; x.f = f;
    unsigned r = x.u + 0x7fffu + ((x.u >> 16) & 1u);   // RNE
    return (short)(r >> 16);
}

__device__ __forceinline__ bf16x8 pack8(float4 a, float4 b) {
    bf16x8 v;
    v[0] = f2bf(a.x); v[1] = f2bf(a.y); v[2] = f2bf(a.z); v[3] = f2bf(a.w);
    v[4] = f2bf(b.x); v[5] = f2bf(b.y); v[6] = f2bf(b.z); v[7] = f2bf(b.w);
    return v;
}

__device__ __forceinline__ float bf2f(short s) {
    union { unsigned u; float f; } x; x.u = ((unsigned)(unsigned short)s) << 16;
    return x.f;
}

// ============================ CSR construction =============================

__global__ __launch_bounds__(256) void hist_k(const int* __restrict__ dst,
                                              int* __restrict__ cnt) {
    int e = blockIdx.x * 256 + threadIdx.x;
    if (e < NE) atomicAdd(&cnt[dst[e]], 1);
}

// exclusive scan within 1024-blocks; block totals to bsum
__global__ __launch_bounds__(1024) void scanA(const int* __restrict__ cnt,
                                              int* __restrict__ rowstart,
                                              int* __restrict__ bsum) {
    __shared__ int s[1024];
    int i = blockIdx.x * 1024 + threadIdx.x;
    int v = (i < NN) ? cnt[i] : 0;
    s[threadIdx.x] = v;
    for (int off = 1; off < 1024; off <<= 1) {
        __syncthreads();
        int t = (threadIdx.x >= off) ? s[threadIdx.x - off] : 0;
        __syncthreads();
        s[threadIdx.x] += t;
    }
    __syncthreads();
    if (i < NN) rowstart[i] = s[threadIdx.x] - v;     // exclusive
    if (threadIdx.x == 1023) bsum[blockIdx.x] = s[1023];
}

// exclusive scan of the 49 block sums (single wave)
__global__ __launch_bounds__(64) void scanB(int* __restrict__ bsum) {
    int l = threadIdx.x;
    int orig = (l < NBLK) ? bsum[l] : 0;
    int v = orig;
    for (int off = 1; off < 64; off <<= 1) {
        int t = __shfl_up(v, off);
        if (l >= off) v += t;
    }
    if (l < NBLK) bsum[l] = v - orig;                 // exclusive
}

__global__ __launch_bounds__(1024) void scanC(int* __restrict__ rowstart,
                                              const int* __restrict__ bsum) {
    int i = blockIdx.x * 1024 + threadIdx.x;
    if (i < NN) rowstart[i] += bsum[blockIdx.x];
}

// fill CSR; post-fill rowstart[u] == end(u) == start(u+1)
__global__ __launch_bounds__(256) void fill_k(const int* __restrict__ src,
                                              const int* __restrict__ dst,
                                              int* __restrict__ rowstart,
                                              int* __restrict__ csr) {
    int e = blockIdx.x * 256 + threadIdx.x;
    if (e < NE) {
        int p = atomicAdd(&rowstart[dst[e]], 1);
        csr[p] = src[e];
    }
}

// ============================ X -> bf16 shadow =============================

__global__ __launch_bounds__(256) void cvt_k(const float* __restrict__ X,
                                             short* __restrict__ Xb) {
    int i = blockIdx.x * 256 + threadIdx.x;   // one thread per 8 floats
    if (i < NN * DIM / 8) {
        const float4* p = (const float4*)(X + (size_t)i * 8);
        *(bf16x8*)(Xb + (size_t)i * 8) = pack8(p[0], p[1]);
    }
}

// ============================ pull aggregation =============================
// one wave per node; lane owns 2 feature slots; register accumulate; one write.

__global__ __launch_bounds__(256) void pull_f32(const float* __restrict__ X,
                                                const int* __restrict__ rowend,
                                                const int* __restrict__ csr,
                                                float* __restrict__ agg) {
    int lane = threadIdx.x & 63;
    int u = (blockIdx.x * 256 + threadIdx.x) >> 6;
    if (u >= NN) return;
    int beg = (u == 0) ? 0 : rowend[u - 1];
    int end = rowend[u];
    float2 a0 = {0.f, 0.f}, a1 = {0.f, 0.f};
    int e = beg;
    for (; e + 1 < end; e += 2) {
        int v0 = csr[e], v1 = csr[e + 1];
        float2 x0 = *(const float2*)(X + (size_t)v0 * DIM + lane * 2);
        float2 x1 = *(const float2*)(X + (size_t)v1 * DIM + lane * 2);
        a0.x += x0.x; a0.y += x0.y;
        a1.x += x1.x; a1.y += x1.y;
    }
    if (e < end) {
        int v0 = csr[e];
        float2 x0 = *(const float2*)(X + (size_t)v0 * DIM + lane * 2);
        a0.x += x0.x; a0.y += x0.y;
    }
    float2 r = {a0.x + a1.x, a0.y + a1.y};
    *(float2*)(agg + (size_t)u * DIM + lane * 2) = r;
}

__global__ __launch_bounds__(256) void pull_bf16(const short* __restrict__ Xb,
                                                 const int* __restrict__ rowend,
                                                 const int* __restrict__ csr,
                                                 float* __restrict__ agg) {
    int lane = threadIdx.x & 63;
    int u = (blockIdx.x * 256 + threadIdx.x) >> 6;
    if (u >= NN) return;
    int beg = (u == 0) ? 0 : rowend[u - 1];
    int end = rowend[u];
    float2 a0 = {0.f, 0.f}, a1 = {0.f, 0.f};
    int e = beg;
    for (; e + 1 < end; e += 2) {
        int v0 = csr[e], v1 = csr[e + 1];
        ushort2 x0 = *(const ushort2*)(Xb + (size_t)v0 * DIM + lane * 2);
        ushort2 x1 = *(const ushort2*)(Xb + (size_t)v1 * DIM + lane * 2);
        a0.x += bf2f(x0.x); a0.y += bf2f(x0.y);
        a1.x += bf2f(x1.x); a1.y += bf2f(x1.y);
    }
    if (e < end) {
        int v0 = csr[e];
        ushort2 x0 = *(const ushort2*)(Xb + (size_t)v0 * DIM + lane * 2);
        a0.x += bf2f(x0.x); a0.y += bf2f(x0.y);
    }
    float2 r = {a0.x + a1.x, a0.y + a1.y};
    *(float2*)(agg + (size_t)u * DIM + lane * 2) = r;
}

// =================== round-1 fallback scatter (ws too small) ===============

__global__ __launch_bounds__(256) void scatter_k(const float* __restrict__ X,
                                                 const int* __restrict__ src,
                                                 const int* __restrict__ dst,
                                                 float* __restrict__ agg) {
    int lane = threadIdx.x & 63;
    int gw = (blockIdx.x * 256 + threadIdx.x) >> 6;
    int nw = (gridDim.x * 256) >> 6;
    for (int e = gw; e < NE; e += nw) {
        int s = src[e];
        int d = dst[e];
        float2 v = *(const float2*)(X + (size_t)s * DIM + lane * 2);
        float* a = agg + (size_t)d * DIM + lane * 2;
        unsafeAtomicAdd(a, v.x);
        unsafeAtomicAdd(a + 1, v.y);
    }
}

// ======================= fused GEMM (same as round 1) ======================
// out = ReLU(X @ Ws^T + agg @ Wn^T + bias); agg aliases out, per-wave rows.

__global__ __launch_bounds__(256) void fused_gemm(
        const float* __restrict__ X,
        const float* __restrict__ agg,
        const float* __restrict__ Ws,
        const float* __restrict__ Wn,
        const float* __restrict__ bias,
        float* __restrict__ out) {
    __shared__ __align__(16) short wlds[2][128][128];

    for (int i = threadIdx.x; i < 128 * 16; i += 256) {
        int row = i >> 4;
        int c8 = (i & 15) << 3;
        int sc = c8 ^ ((row & 15) << 3);
        const float4* ps = (const float4*)(Ws + row * DIM + c8);
        *(bf16x8*)&wlds[0][row][sc] = pack8(ps[0], ps[1]);
        const float4* pn = (const float4*)(Wn + row * DIM + c8);
        *(bf16x8*)&wlds[1][row][sc] = pack8(pn[0], pn[1]);
    }
    __syncthreads();

    int lane = threadIdx.x & 63;
    int wv = threadIdx.x >> 6;
    int n0 = blockIdx.x * 64 + wv * 16;
    int arow = n0 + (lane & 15);
    int rowc = arow < NN ? arow : (NN - 1);
    const float* xr = X + (size_t)rowc * DIM + (lane >> 4) * 8;
    const float* ar = agg + (size_t)rowc * DIM + (lane >> 4) * 8;

    f32x4 acc[8] = {};

    #pragma unroll
    for (int ks = 0; ks < 4; ++ks) {
        int k0 = ks * 32;
        float4 xa = *(const float4*)(xr + k0);
        float4 xb = *(const float4*)(xr + k0 + 4);
        bf16x8 afx = pack8(xa, xb);
        float4 ga = *(const float4*)(ar + k0);
        float4 gb = *(const float4*)(ar + k0 + 4);
        bf16x8 afg = pack8(ga, gb);

        int bcol = k0 + (lane >> 4) * 8;
        #pragma unroll
        for (int ot = 0; ot < 8; ++ot) {
            int brow = ot * 16 + (lane & 15);
            int sc = bcol ^ ((brow & 15) << 3);
            bf16x8 bs = *(const bf16x8*)&wlds[0][brow][sc];
            bf16x8 bn = *(const bf16x8*)&wlds[1][brow][sc];
            acc[ot] = __builtin_amdgcn_mfma_f32_16x16x32_bf16(afx, bs, acc[ot], 0, 0, 0);
            acc[ot] = __builtin_amdgcn_mfma_f32_16x16x32_bf16(afg, bn, acc[ot], 0, 0, 0);
        }
    }

    int col0 = lane & 15;
    int rbase = n0 + (lane >> 4) * 4;
    #pragma unroll
    for (int ot = 0; ot < 8; ++ot) {
        int col = ot * 16 + col0;
        float bv = bias[col];
        #pragma unroll
        for (int i = 0; i < 4; ++i) {
            int r = rbase + i;
            if (r < NN) out[(size_t)r * DIM + col] = fmaxf(acc[ot][i] + bv, 0.f);
        }
    }
}

// ===========================================================================

extern "C" void kernel_launch(void* const* d_in, const int* in_sizes, int n_in,
                              void* d_out, int out_size, void* d_ws, size_t ws_size,
                              hipStream_t stream) {
    const float* X    = (const float*)d_in[0];
    const int*   src  = (const int*)  d_in[1];
    const int*   dst  = (const int*)  d_in[2];
    const float* Ws   = (const float*)d_in[3];
    const float* Wn   = (const float*)d_in[4];
    const float* bias = (const float*)d_in[5];
    float* out = (float*)d_out;

    // ws layout (ints): cnt[50048] | rowstart[50048] | bsum[64] | csr[800000]
    // then optionally Xb (bf16, NN*DIM shorts)
    const size_t REQ  = (size_t)(50048 + 50048 + 64 + 800000) * 4;   // 3,600,640
    const size_t REQB = REQ + (size_t)NN * DIM * 2;                  // 16,400,640

    if (ws_size < REQ) {
        // fallback: round-1 atomic scatter path
        hipMemsetAsync(out, 0, (size_t)NN * DIM * sizeof(float), stream);
        scatter_k<<<2048, 256, 0, stream>>>(X, src, dst, out);
        fused_gemm<<<(NN + 63) / 64, 256, 0, stream>>>(X, out, Ws, Wn, bias, out);
        return;
    }

    int* cnt      = (int*)d_ws;
    int* rowstart = cnt + 50048;
    int* bsum     = rowstart + 50048;
    int* csr      = bsum + 64;
    short* Xb     = (short*)(csr + 800000);

    hipMemsetAsync(cnt, 0, 50048 * sizeof(int), stream);
    hist_k<<<(NE + 255) / 256, 256, 0, stream>>>(dst, cnt);
    scanA<<<NBLK, 1024, 0, stream>>>(cnt, rowstart, bsum);
    scanB<<<1, 64, 0, stream>>>(bsum);
    scanC<<<NBLK, 1024, 0, stream>>>(rowstart, bsum);
    fill_k<<<(NE + 255) / 256, 256, 0, stream>>>(src, dst, rowstart, csr);

    if (ws_size >= REQB) {
        cvt_k<<<(NN * DIM / 8 + 255) / 256, 256, 0, stream>>>(X, Xb);
        pull_bf16<<<(NN * 64 + 255) / 256, 256, 0, stream>>>(Xb, rowstart, csr, out);
    } else {
        pull_f32<<<(NN * 64 + 255) / 256, 256, 0, stream>>>(X, rowstart, csr, out);
    }

    fused_gemm<<<(NN + 63) / 64, 256, 0, stream>>>(X, out, Ws, Wn, bias, out);
}